// Round 6
// baseline (489.859 us; speedup 1.0000x reference)
//
#include <hip/hip_runtime.h>
#include <hip/hip_bf16.h>

typedef __hip_bfloat16 bf16;
using short8  = __attribute__((ext_vector_type(8))) short;
using floatx4 = __attribute__((ext_vector_type(4))) float;

__device__ __forceinline__ float b2f(bf16 v) { return __bfloat162float(v); }
__device__ __forceinline__ bf16 f2b(float v) { return __float2bfloat16(v); }
__device__ __forceinline__ float s2f(short s) {
    return __uint_as_float(((unsigned)(unsigned short)s) << 16);
}
__device__ __forceinline__ unsigned short fbits(float v) {
    bf16 b = f2b(v);
    return *(unsigned short*)&b;
}

constexpr int H = 256, W = 256, Hh = 128, Wh = 128, C8 = 512;
constexpr int HWh = Hh * Wh;   // 16384
constexpr int HWf = H * W;     // 65536
constexpr int ICP = 40;        // LDS ic stride (32+8 pad): lane stride 20 dwords -> 2-way (free)

// ---------------------------------------------------------------- weight swizzles
// conv3x3 weights -> [tap][kc][g][nt][lane][8]  (exact MFMA B-fragment order)
template<int OC, int IC>
__global__ __launch_bounds__(256) void prep_wrT(const float* __restrict__ w, bf16* __restrict__ wrT) {
    int idx = blockIdx.x * 256 + threadIdx.x;
    if (idx >= 9 * OC * IC) return;
    constexpr int G = OC / 64, KC = IC / 32;
    int j = idx & 7;
    int l = (idx >> 3) & 63;
    int nt = (idx >> 9) & 3;
    int rest = idx >> 11;
    int g = rest % G;
    int rest2 = rest / G;
    int kc = rest2 % KC;
    int tap = rest2 / KC;
    int oc = g * 64 + nt * 16 + (l & 15);
    int ic = kc * 32 + (l >> 4) * 8 + j;
    wrT[idx] = f2b(w[(oc * IC + ic) * 9 + tap]);
}

// w_1x1 * cal_scale -> [b][kc 16][g8 8][nt 4][lane][8]
__global__ __launch_bounds__(256) void prep_w1sT(const float* __restrict__ w1,
                                                 const float* __restrict__ scale,
                                                 bf16* __restrict__ w1sT) {
    int idx = blockIdx.x * 256 + threadIdx.x;   // 4*512*512
    int j = idx & 7;
    int l = (idx >> 3) & 63;
    int nt = (idx >> 9) & 7;
    int g = (idx >> 12) & 3;
    int kc = (idx >> 14) & 15;
    int b = idx >> 18;
    int oc = g * 128 + nt * 16 + (l & 15);
    int ic = kc * 32 + (l >> 4) * 8 + j;
    w1sT[idx] = f2b(w1[oc * 512 + ic] * scale[b * 512 + ic]);
}

// w_final -> [kc 2][nt 4][lane][8]
__global__ __launch_bounds__(256) void prep_wfrT(const float* __restrict__ wf, bf16* __restrict__ wfrT) {
    int idx = blockIdx.x * 256 + threadIdx.x;   // 4096
    int j = idx & 7;
    int l = (idx >> 3) & 63;
    int nt = (idx >> 9) & 3;
    int kc = idx >> 11;
    int oc = nt * 16 + (l & 15);
    int ic = kc * 32 + (l >> 4) * 8 + j;
    wfrT[idx] = f2b(wf[oc * 64 + ic]);
}

// ---------------------------------------------------------------- bwt, LDS-transposed
constexpr int XROW = 130;
__global__ __launch_bounds__(256, 4) void bwt_nhwc(const float* __restrict__ x, bf16* __restrict__ A) {
    __shared__ unsigned short sX[2 * 64 * XROW];
    int bx = blockIdx.x;
    int i = bx >> 1, j0 = (bx & 1) * 64;
    int b = blockIdx.z;
    int tid = threadIdx.x;
    for (int k = 0; k < 16; k++) {
        int e = tid + k * 256;
        int w4 = e & 31, r = (e >> 5) & 1, c = e >> 6;
        float4 v = *(const float4*)(x + (((size_t)(b * 64 + c) * H + 2 * i + r) * W) + j0 * 2 + w4 * 4);
        unsigned lo = ((unsigned)fbits(v.y) << 16) | fbits(v.x);
        unsigned hi = ((unsigned)fbits(v.w) << 16) | fbits(v.z);
        unsigned short* dst = sX + (r * 64 + c) * XROW + w4 * 4;
        *(unsigned*)(dst) = lo;
        *(unsigned*)(dst + 2) = hi;
    }
    __syncthreads();
    int c = tid & 63, wid = tid >> 6;
    for (int k = 0; k < 16; k++) {
        int jr = wid * 16 + k;
        unsigned ev = *(const unsigned*)(sX + c * XROW + jr * 2);
        unsigned od = *(const unsigned*)(sX + (64 + c) * XROW + jr * 2);
        float x1 = s2f((short)(ev & 0xffff)) * 0.5f;
        float x3 = s2f((short)(ev >> 16)) * 0.5f;
        float x2 = s2f((short)(od & 0xffff)) * 0.5f;
        float x4 = s2f((short)(od >> 16)) * 0.5f;
        float v[8];
        v[0] =  x1 + x2 + x3 + x4;
        v[1] = -x1 - x2 + x3 + x4;
        v[2] = -x1 + x2 - x3 + x4;
        v[3] =  x1 - x2 - x3 + x4;
        v[4] =  x1 + x2 - x3 - x4;
        v[5] = -x1 + x2 + x3 - x4;
        v[6] =  x1 - x2 + x3 - x4;
        v[7] = -x1 - x2 - x3 - x4;
        size_t base = ((size_t)((b * Hh + i) * Wh) + j0 + jr) * 512 + c;
        #pragma unroll
        for (int band = 0; band < 8; band++)
            A[base + band * 64] = f2b(v[band]);
    }
}

// ---------------------------------------------------------------- conv3x3 MFMA, dbuf LDS + direct-global weights
template<int IC, int OC, int HW, int TR, bool RELU, int MINW>
__global__ __launch_bounds__(256, MINW) void conv3x3_mfma(const bf16* __restrict__ in,
                                                          const bf16* __restrict__ wrT,
                                                          bf16* __restrict__ out) {
    constexpr int MT = TR / 4, NKC = IC / 32, G = OC / 64;
    constexpr int CELLS = (TR + 2) * 18;
    constexpr int NLD = (CELLS * 4 + 255) / 256;
    __shared__ bf16 sIn[2][CELLS * ICP];

    const int tilesX = HW / 16;
    int tX = (blockIdx.x % tilesX) * 16;
    int tY = (blockIdx.x / tilesX) * TR;
    int g = blockIdx.y;
    int b = blockIdx.z;
    int tid = threadIdx.x;
    int lane = tid & 63, wid = tid >> 6;
    int m = lane & 15, quad = lane >> 4;

    floatx4 acc[MT][4];
    #pragma unroll
    for (int i = 0; i < MT; i++)
        #pragma unroll
        for (int j = 0; j < 4; j++)
            acc[i][j] = (floatx4){0.f, 0.f, 0.f, 0.f};

    const bf16* inB = in + (size_t)b * HW * HW * IC;

    auto load_tile = [&](int kc, short8* tmp) {
        #pragma unroll
        for (int k = 0; k < NLD; k++) {
            int e = tid + k * 256;
            tmp[k] = (short8){0, 0, 0, 0, 0, 0, 0, 0};
            if (e < CELLS * 4) {
                int q = e & 3, cell = e >> 2;
                int r = cell / 18, c = cell - r * 18;
                int gr = tY + r - 1, gc = tX + c - 1;
                if (gr >= 0 && gr < HW && gc >= 0 && gc < HW)
                    tmp[k] = *(const short8*)(inB + (size_t)(gr * HW + gc) * IC + kc * 32 + q * 8);
            }
        }
    };
    auto write_tile = [&](int buf, short8* tmp) {
        #pragma unroll
        for (int k = 0; k < NLD; k++) {
            int e = tid + k * 256;
            if (e < CELLS * 4) {
                int q = e & 3, cell = e >> 2;
                *(short8*)(sIn[buf] + cell * ICP + q * 8) = tmp[k];
            }
        }
    };

    {
        short8 t0[NLD];
        load_tile(0, t0);
        write_tile(0, t0);
    }
    for (int kc = 0; kc < NKC; kc++) {
        short8 nxt[NLD];
        __syncthreads();
        bool pf = (kc + 1 < NKC);
        if (pf) load_tile(kc + 1, nxt);        // issue loads; consumed after compute
        const bf16* sbuf = sIn[kc & 1];
        #pragma unroll
        for (int dx = 0; dx < 3; dx++) {
            short8 arow[MT + 2];
            #pragma unroll
            for (int i = 0; i < MT + 2; i++)
                arow[i] = *(const short8*)(sbuf + ((wid * MT + i) * 18 + m + dx) * ICP + quad * 8);
            #pragma unroll
            for (int dy = 0; dy < 3; dy++) {
                int tap = dy * 3 + dx;
                const bf16* wt = wrT + ((size_t)((tap * NKC + kc) * G + g) * 4) * 512;
                short8 bfr[4];
                #pragma unroll
                for (int nt = 0; nt < 4; nt++)
                    bfr[nt] = *(const short8*)(wt + nt * 512 + lane * 8);
                #pragma unroll
                for (int mt = 0; mt < MT; mt++)
                    #pragma unroll
                    for (int nt = 0; nt < 4; nt++)
                        acc[mt][nt] = __builtin_amdgcn_mfma_f32_16x16x32_bf16(arow[mt + dy], bfr[nt], acc[mt][nt], 0, 0, 0);
            }
        }
        if (pf) write_tile((kc + 1) & 1, nxt);
    }
    #pragma unroll
    for (int mt = 0; mt < MT; mt++) {
        int row = tY + wid * MT + mt;
        #pragma unroll
        for (int nt = 0; nt < 4; nt++) {
            int oc = g * 64 + nt * 16 + m;
            #pragma unroll
            for (int reg = 0; reg < 4; reg++) {
                int col = tX + quad * 4 + reg;
                float v = acc[mt][nt][reg];
                if (RELU) v = fmaxf(v, 0.f);
                out[((size_t)(b * HW + row) * HW + col) * OC + oc] = f2b(v);
            }
        }
    }
}

// ---------------------------------------------------------------- conv1x1 MFMA: T2 x w1sT, smap in epilogue, + A residual
// block: 256 px x 64 oc
__global__ __launch_bounds__(256, 3) void conv1x1_mfma(const bf16* __restrict__ t3,
                                                       const float* __restrict__ smap,
                                                       const bf16* __restrict__ w1sT,
                                                       bf16* __restrict__ A) {
    __shared__ bf16 sX[2][256 * ICP];
    int p0 = blockIdx.x * 256;
    int g8 = blockIdx.y;                       // 64-oc group, 0..7
    int b = blockIdx.z;
    int tid = threadIdx.x;
    int lane = tid & 63, wid = tid >> 6;
    int m = lane & 15, quad = lane >> 4;
    const bf16* tB = t3 + ((size_t)b << 14) * 512;
    const float* sm = smap + (b << 14);

    floatx4 acc[4][4];
    #pragma unroll
    for (int i = 0; i < 4; i++)
        #pragma unroll
        for (int j = 0; j < 4; j++)
            acc[i][j] = (floatx4){0.f, 0.f, 0.f, 0.f};

    auto load_x = [&](int kc, short8* tmp) {
        #pragma unroll
        for (int k = 0; k < 4; k++) {
            int e = tid + k * 256;
            int q = e & 3, p = e >> 2;
            tmp[k] = *(const short8*)(tB + (size_t)(p0 + p) * 512 + kc * 32 + q * 8);
        }
    };
    auto write_x = [&](int buf, short8* tmp) {
        #pragma unroll
        for (int k = 0; k < 4; k++) {
            int e = tid + k * 256;
            int q = e & 3, p = e >> 2;
            *(short8*)(sX[buf] + p * ICP + q * 8) = tmp[k];
        }
    };

    {
        short8 t0[4];
        load_x(0, t0);
        write_x(0, t0);
    }
    for (int kc = 0; kc < 16; kc++) {
        short8 nxt[4];
        __syncthreads();
        bool pf = (kc + 1 < 16);
        if (pf) load_x(kc + 1, nxt);
        const bf16* sbuf = sX[kc & 1];
        const bf16* wt = w1sT + ((size_t)(((b * 16 + kc) * 8 + g8) * 4)) * 512;
        short8 bfr[4];
        #pragma unroll
        for (int nt = 0; nt < 4; nt++)
            bfr[nt] = *(const short8*)(wt + nt * 512 + lane * 8);
        #pragma unroll
        for (int mt = 0; mt < 4; mt++) {
            short8 afr = *(const short8*)(sbuf + ((wid * 4 + mt) * 16 + m) * ICP + quad * 8);
            #pragma unroll
            for (int nt = 0; nt < 4; nt++)
                acc[mt][nt] = __builtin_amdgcn_mfma_f32_16x16x32_bf16(afr, bfr[nt], acc[mt][nt], 0, 0, 0);
        }
        if (pf) write_x((kc + 1) & 1, nxt);
    }
    bf16* AB = A + ((size_t)b << 14) * 512;
    #pragma unroll
    for (int mt = 0; mt < 4; mt++) {
        float smv[4];
        *(float4*)smv = *(const float4*)(sm + p0 + wid * 64 + mt * 16 + quad * 4);
        #pragma unroll
        for (int nt = 0; nt < 4; nt++) {
            int oc = g8 * 64 + nt * 16 + m;
            #pragma unroll
            for (int reg = 0; reg < 4; reg++) {
                int p = p0 + wid * 64 + mt * 16 + quad * 4 + reg;
                size_t a = (size_t)p * 512 + oc;
                AB[a] = f2b(acc[mt][nt][reg] * smv[reg] + b2f(AB[a]));
            }
        }
    }
}

// ---------------------------------------------------------------- sal: per-pixel channel max/mean
__global__ __launch_bounds__(256) void sal_pool(const bf16* __restrict__ t2, float* __restrict__ pool) {
    int pix = blockIdx.x * 4 + (threadIdx.x >> 6);
    int lane = threadIdx.x & 63;
    short8 v = *(const short8*)(t2 + (size_t)pix * 512 + lane * 8);
    float mx = -1e30f, sm = 0.f;
    #pragma unroll
    for (int i = 0; i < 8; i++) {
        float f = s2f(v[i]);
        mx = fmaxf(mx, f);
        sm += f;
    }
    #pragma unroll
    for (int off = 32; off > 0; off >>= 1) {
        mx = fmaxf(mx, __shfl_xor(mx, off));
        sm += __shfl_xor(sm, off);
    }
    if (lane == 0) {
        int b = pix >> 14, px = pix & (HWh - 1);
        pool[((size_t)(b * 2) << 14) + px] = mx;
        pool[((size_t)(b * 2 + 1) << 14) + px] = sm * (1.f / 512.f);
    }
}

// ---------------------------------------------------------------- sal: 5x5 conv + sigmoid
__global__ __launch_bounds__(256) void sal_conv(const float* __restrict__ pool,
                                                const float* __restrict__ wsal,
                                                float* __restrict__ smap) {
    int p = blockIdx.x * 256 + threadIdx.x;
    int b = p >> 14, px = p & (HWh - 1);
    int iy = px >> 7, ix = px & 127;
    float acc = 0.f;
    #pragma unroll
    for (int ch = 0; ch < 2; ch++)
        #pragma unroll
        for (int dy = 0; dy < 5; dy++)
            #pragma unroll
            for (int dx = 0; dx < 5; dx++) {
                int gy = iy + dy - 2, gx = ix + dx - 2;
                if (gy >= 0 && gy < Hh && gx >= 0 && gx < Wh)
                    acc += pool[((size_t)(b * 2 + ch) << 14) + gy * Wh + gx] *
                           wsal[ch * 25 + dy * 5 + dx];
            }
    smap[p] = 1.f / (1.f + expf(-acc));
}

// ---------------------------------------------------------------- chsum[b][c] = sum_px T2[px,c]*smap[px]
__global__ __launch_bounds__(256) void sal_wsum(const bf16* __restrict__ t2,
                                                const float* __restrict__ smap,
                                                float* __restrict__ chsum) {
    int b = blockIdx.y;
    int p0 = blockIdx.x * 32;
    int t = threadIdx.x;
    float s0 = 0.f, s1 = 0.f;
    const bf16* tB = t2 + ((size_t)b << 14) * 512;
    #pragma unroll 4
    for (int k = 0; k < 32; k++) {
        int pix = p0 + k;
        float sc = smap[(b << 14) + pix];
        unsigned v = *(const unsigned*)(tB + (size_t)pix * 512 + 2 * t);
        s0 += s2f((short)(v & 0xffff)) * sc;
        s1 += s2f((short)(v >> 16)) * sc;
    }
    atomicAdd(&chsum[b * 512 + 2 * t], s0);
    atomicAdd(&chsum[b * 512 + 2 * t + 1], s1);
}

// ---------------------------------------------------------------- cal MLP -> sigmoid scale per (b,c)
__global__ __launch_bounds__(512) void cal_kernel(const float* __restrict__ chsum,
                                                  const float* __restrict__ wca1,
                                                  const float* __restrict__ wca2,
                                                  float* __restrict__ scale) {
    int b = blockIdx.x;
    __shared__ float sMean[512];
    __shared__ float sH[32];
    sMean[threadIdx.x] = chsum[b * C8 + threadIdx.x] * (1.f / 16384.f);
    __syncthreads();
    if (threadIdx.x < 32) {
        float a = 0.f;
        for (int cc = 0; cc < 512; cc++)
            a += wca1[threadIdx.x * 512 + cc] * sMean[cc];
        sH[threadIdx.x] = fmaxf(a, 0.f);
    }
    __syncthreads();
    float a = 0.f;
    #pragma unroll
    for (int j = 0; j < 32; j++)
        a += wca2[threadIdx.x * 32 + j] * sH[j];
    scale[b * C8 + threadIdx.x] = 1.f / (1.f + expf(-a));
}

// ---------------------------------------------------------------- ibwt: A NHWC -> E NHWC
__global__ __launch_bounds__(256) void ibwt_nhwc(const bf16* __restrict__ A, bf16* __restrict__ E) {
    int idx = blockIdx.x * 256 + threadIdx.x;
    int c = idx & 63;
    int j = (idx >> 6) & 127;
    int i = (idx >> 13) & 127;
    int b = idx >> 20;
    size_t base = (size_t)(idx >> 6) * 512 + c;
    float xs[8];
    #pragma unroll
    for (int k = 0; k < 8; k++)
        xs[k] = b2f(A[base + k * 64]) * 0.5f;
    float a00 = xs[0] - xs[1] - xs[2] + xs[3] + xs[4] - xs[5] + xs[6] - xs[7];
    float a10 = xs[0] - xs[1] + xs[2] - xs[3] - xs[4] + xs[5] - xs[6] + xs[7];
    float a01 = xs[0] + xs[1] - xs[2] - xs[3] - xs[4] - xs[5] + xs[6] + xs[7];
    float a11 = xs[0] + xs[1] + xs[2] + xs[3] + xs[4] + xs[5] + xs[6] + xs[7];
    bf16* Ep = E + ((size_t)((b * H + 2 * i) * W + 2 * j)) * 64 + c;
    Ep[0]           = f2b(a00);
    Ep[64]          = f2b(a01);
    Ep[W * 64]      = f2b(a10);
    Ep[W * 64 + 64] = f2b(a11);
}

// ---------------------------------------------------------------- final: relu(conv3x3(E)) + w_final@x -> NCHW fp32
__global__ __launch_bounds__(256, 3) void final_mfma(const bf16* __restrict__ E,
                                                     const bf16* __restrict__ wr3T,
                                                     const float* __restrict__ x,
                                                     const bf16* __restrict__ wfrT,
                                                     float* __restrict__ out) {
    constexpr int CELLS = 18 * 18;
    __shared__ bf16 sIn[2][CELLS * ICP];
    const int tilesX = W / 16;
    int tX = (blockIdx.x % tilesX) * 16;
    int tY = (blockIdx.x / tilesX) * 16;
    int b = blockIdx.z;
    int tid = threadIdx.x;
    int lane = tid & 63, wid = tid >> 6;
    int m = lane & 15, quad = lane >> 4;

    floatx4 acc[4][4];
    #pragma unroll
    for (int i = 0; i < 4; i++)
        #pragma unroll
        for (int j = 0; j < 4; j++)
            acc[i][j] = (floatx4){0.f, 0.f, 0.f, 0.f};

    const bf16* inB = E + (size_t)b * HWf * 64;

    auto load_e = [&](int kc, short8* tmp) {
        #pragma unroll
        for (int k = 0; k < 6; k++) {
            int e = tid + k * 256;
            tmp[k] = (short8){0, 0, 0, 0, 0, 0, 0, 0};
            if (e < CELLS * 4) {
                int q = e & 3, cell = e >> 2;
                int r = cell / 18, c = cell - r * 18;
                int gr = tY + r - 1, gc = tX + c - 1;
                if (gr >= 0 && gr < H && gc >= 0 && gc < W)
                    tmp[k] = *(const short8*)(inB + (size_t)(gr * W + gc) * 64 + kc * 32 + q * 8);
            }
        }
    };
    auto write_e = [&](int buf, short8* tmp) {
        #pragma unroll
        for (int k = 0; k < 6; k++) {
            int e = tid + k * 256;
            if (e < CELLS * 4) {
                int q = e & 3, cell = e >> 2;
                *(short8*)(sIn[buf] + cell * ICP + q * 8) = tmp[k];
            }
        }
    };
    auto compute_e = [&](int kc, int buf) {
        const bf16* sbuf = sIn[buf];
        #pragma unroll
        for (int dx = 0; dx < 3; dx++) {
            short8 arow[6];
            #pragma unroll
            for (int i = 0; i < 6; i++)
                arow[i] = *(const short8*)(sbuf + ((wid * 4 + i) * 18 + m + dx) * ICP + quad * 8);
            #pragma unroll
            for (int dy = 0; dy < 3; dy++) {
                int tap = dy * 3 + dx;
                const bf16* wt = wr3T + ((size_t)(tap * 2 + kc) * 4) * 512;
                short8 bfr[4];
                #pragma unroll
                for (int nt = 0; nt < 4; nt++)
                    bfr[nt] = *(const short8*)(wt + nt * 512 + lane * 8);
                #pragma unroll
                for (int mt = 0; mt < 4; mt++)
                    #pragma unroll
                    for (int nt = 0; nt < 4; nt++)
                        acc[mt][nt] = __builtin_amdgcn_mfma_f32_16x16x32_bf16(arow[mt + dy], bfr[nt], acc[mt][nt], 0, 0, 0);
            }
        }
    };
    auto load_xx = [&](int kc, float4* xt) {
        #pragma unroll
        for (int k = 0; k < 8; k++) {
            int e = tid + k * 256;
            int c4 = e & 3, r = (e >> 2) & 15, ic = e >> 6;
            xt[k] = *(const float4*)(x + ((size_t)(b * 64 + kc * 32 + ic) * H + tY + r) * W + tX + c4 * 4);
        }
    };
    auto write_xx = [&](int buf, float4* xt) {
        #pragma unroll
        for (int k = 0; k < 8; k++) {
            int e = tid + k * 256;
            int c4 = e & 3, r = (e >> 2) & 15, ic = e >> 6;
            bf16* dst = sIn[buf] + ((r + 1) * 18 + c4 * 4 + 1) * ICP + ic;
            dst[0]       = f2b(xt[k].x);
            dst[ICP]     = f2b(xt[k].y);
            dst[2 * ICP] = f2b(xt[k].z);
            dst[3 * ICP] = f2b(xt[k].w);
        }
    };
    auto compute_x = [&](int kc, int buf) {
        const bf16* wt = wfrT + (size_t)(kc * 4) * 512;
        short8 bfr[4];
        #pragma unroll
        for (int nt = 0; nt < 4; nt++)
            bfr[nt] = *(const short8*)(wt + nt * 512 + lane * 8);
        #pragma unroll
        for (int mt = 0; mt < 4; mt++) {
            short8 afr = *(const short8*)(sIn[buf] + ((wid * 4 + mt + 1) * 18 + m + 1) * ICP + quad * 8);
            #pragma unroll
            for (int nt = 0; nt < 4; nt++)
                acc[mt][nt] = __builtin_amdgcn_mfma_f32_16x16x32_bf16(afr, bfr[nt], acc[mt][nt], 0, 0, 0);
        }
    };

    {
        short8 t0[6];
        load_e(0, t0);
        write_e(0, t0);
        load_e(1, t0);
        write_e(1, t0);
    }
    __syncthreads();
    compute_e(0, 0);
    __syncthreads();
    {
        float4 xt[8];
        load_xx(0, xt);
        compute_e(1, 1);
        #pragma unroll
        for (int i = 0; i < 4; i++)
            #pragma unroll
            for (int j = 0; j < 4; j++)
                #pragma unroll
                for (int r = 0; r < 4; r++)
                    acc[i][j][r] = fmaxf(acc[i][j][r], 0.f);
        write_xx(0, xt);
    }
    __syncthreads();
    {
        float4 xt[8];
        load_xx(1, xt);
        compute_x(0, 0);
        write_xx(1, xt);
    }
    __syncthreads();
    compute_x(1, 1);

    #pragma unroll
    for (int mt = 0; mt < 4; mt++) {
        int gr = tY + wid * 4 + mt;
        #pragma unroll
        for (int nt = 0; nt < 4; nt++) {
            int oc = nt * 16 + m;
            *(floatx4*)(out + ((size_t)(b * 64 + oc) * H + gr) * W + tX + quad * 4) = acc[mt][nt];
        }
    }
}

// ---------------------------------------------------------------- launch
extern "C" void kernel_launch(void* const* d_in, const int* in_sizes, int n_in,
                              void* d_out, int out_size, void* d_ws, size_t ws_size,
                              hipStream_t stream) {
    const float* x       = (const float*)d_in[0];
    const float* w_body1 = (const float*)d_in[1];
    const float* w_body2 = (const float*)d_in[2];
    const float* w_sal   = (const float*)d_in[3];
    const float* w_ca1   = (const float*)d_in[4];
    const float* w_ca2   = (const float*)d_in[5];
    const float* w_1x1   = (const float*)d_in[6];
    const float* w_3x3   = (const float*)d_in[7];
    const float* w_final = (const float*)d_in[8];

    char* ws = (char*)d_ws;
    bf16*  A     = (bf16*)(ws + 0);            // 67,108,864  NHWC (B,128,128,512)
    bf16*  T2    = (bf16*)(ws + 67108864);     // 67,108,864  NHWC body2 out; E aliases later
    bf16*  T1    = (bf16*)(ws + 134217728);    //  8,388,608  body1 out (dead after body2)
    float* pool  = (float*)(ws + 134217728);   //    524,288 (T1 dead by then)
    float* smap  = (float*)(ws + 134742016);   //    262,144
    float* chsum = (float*)(ws + 135004160);   //      8,192
    float* scale = (float*)(ws + 135012352);   //      8,192
    bf16*  w1sT  = (bf16*)(ws + 135020544);    //  2,097,152
    bf16*  wr3T  = (bf16*)(ws + 137117696);    //     73,728
    bf16*  wfrT  = (bf16*)(ws + 137191424);    //      8,192
    bf16*  E     = T2;
    bf16*  wr1T  = (bf16*)d_out;               //    589,824 (parked in dead d_out)
    bf16*  wr2T  = (bf16*)((char*)d_out + 589824);

    prep_wrT<64, 512><<<1152, 256, 0, stream>>>(w_body1, wr1T);
    prep_wrT<512, 64><<<1152, 256, 0, stream>>>(w_body2, wr2T);
    bwt_nhwc<<<dim3(256, 1, 4), 256, 0, stream>>>(x, A);
    conv3x3_mfma<512, 64, 128, 4, true, 4><<<dim3(256, 1, 4), 256, 0, stream>>>(A, wr1T, T1);
    conv3x3_mfma<64, 512, 128, 16, false, 3><<<dim3(64, 8, 4), 256, 0, stream>>>(T1, wr2T, T2);
    sal_pool<<<16384, 256, 0, stream>>>(T2, pool);
    sal_conv<<<256, 256, 0, stream>>>(pool, w_sal, smap);
    hipMemsetAsync(chsum, 0, 4 * 512 * sizeof(float), stream);
    sal_wsum<<<dim3(512, 4), 256, 0, stream>>>(T2, smap, chsum);
    cal_kernel<<<4, 512, 0, stream>>>(chsum, w_ca1, w_ca2, scale);
    prep_w1sT<<<4096, 256, 0, stream>>>(w_1x1, scale, w1sT);
    prep_wrT<64, 64><<<144, 256, 0, stream>>>(w_3x3, wr3T);
    prep_wfrT<<<16, 256, 0, stream>>>(w_final, wfrT);
    conv1x1_mfma<<<dim3(64, 8, 4), 256, 0, stream>>>(T2, smap, w1sT, A);
    ibwt_nhwc<<<16384, 256, 0, stream>>>(A, E);
    final_mfma<<<dim3(256, 1, 4), 256, 0, stream>>>(E, wr3T, x, wfrT, (float*)d_out);
}